// Round 2
// baseline (286.462 us; speedup 1.0000x reference)
//
#include <hip/hip_runtime.h>
#include <stdint.h>

// ---------------------------------------------------------------------------
// MultiHeadedAttention (B=2,S=2048,D=1024,H=16,DK=64)
//   INPUTS fp32 (query,key,value,Wqkv,Wout) + int32 mask; OUTPUT fp32.
// R9:
//   * GEMM: 2-phase double-buffered LDS (stage t+1 before compute t, ONE
//     barrier/step -> prefetch latency hidden under MFMA), launch_bounds
//     min-waves pinned (3 blocks/CU QKV, 2 out-proj).
//   * attn: V-tile stride 66 (V-transpose b32 stores were 8-way bank
//     conflicts at stride 72 -> now 2-way, free); mask bitwords prefetched
//     one tile ahead (were a cold global load on the softmax critical path).
// ---------------------------------------------------------------------------

typedef __bf16 bf16;
typedef __bf16 bf16x8 __attribute__((ext_vector_type(8)));
typedef __bf16 bf16x4 __attribute__((ext_vector_type(4)));
typedef float f32x4 __attribute__((ext_vector_type(4)));

#define MFMA16(a, b, c) __builtin_amdgcn_mfma_f32_16x16x32_bf16((a), (b), (c), 0, 0, 0)
#define EXP2(x) __builtin_amdgcn_exp2f(x)

static constexpr int BATCH = 2;
static constexpr int SEQ = 2048;
static constexpr int DIM = 1024;
static constexpr int DK = 64;
// q is pre-scaled by 1/sqrt(DK) * log2(e) in the QKV GEMM epilogue (z==0)
static constexpr float QSCALE = 0.125f * 1.44269504088896340736f;

// ---- async global->LDS, 16 B per lane -------------------------------------
__device__ inline void gload16(const void* g, void* l) {
  __builtin_amdgcn_global_load_lds((const __attribute__((address_space(1))) void*)g,
                                   (__attribute__((address_space(3))) void*)l, 16, 0, 0);
}

// ---------------- mask (int32 0/1) -> bitmask, 1 bit per element -----------
__global__ __launch_bounds__(256) void mask_bits_kernel(const int* __restrict__ mask,
                                                        unsigned long long* __restrict__ bits) {
  int idx = blockIdx.x * 256 + threadIdx.x;  // grid covers exactly B*S*S
  int m = mask[idx];
  unsigned long long bal = __ballot(m != 0);
  if ((threadIdx.x & 63) == 0) bits[idx >> 6] = bal;
}

// ---------------- fp32 -> bf16 convert (5 tensors, one launch) -------------
__global__ __launch_bounds__(256) void cvt_bf16_kernel(const float* __restrict__ s0,
                                                       const float* __restrict__ s1,
                                                       const float* __restrict__ s2,
                                                       const float* __restrict__ s3,
                                                       const float* __restrict__ s4,
                                                       bf16* __restrict__ d0, bf16* __restrict__ d1,
                                                       bf16* __restrict__ d2, bf16* __restrict__ d3,
                                                       bf16* __restrict__ d4) {
  const int y = blockIdx.y;
  const float* s = (y == 0) ? s0 : (y == 1) ? s1 : (y == 2) ? s2 : (y == 3) ? s3 : s4;
  bf16* d = (y == 0) ? d0 : (y == 1) ? d1 : (y == 2) ? d2 : (y == 3) ? d3 : d4;
  const int n8 = (y < 3) ? (BATCH * SEQ * DIM / 8) : (DIM * DIM / 8);
  for (int i = blockIdx.x * 256 + threadIdx.x; i < n8; i += gridDim.x * 256) {
    const float4 a = ((const float4*)s)[2 * i];
    const float4 b = ((const float4*)s)[2 * i + 1];
    bf16x8 v;
    v[0] = (bf16)a.x;
    v[1] = (bf16)a.y;
    v[2] = (bf16)a.z;
    v[3] = (bf16)a.w;
    v[4] = (bf16)b.x;
    v[5] = (bf16)b.y;
    v[6] = (bf16)b.z;
    v[7] = (bf16)b.w;
    ((bf16x8*)d)[i] = v;
  }
}

// ---------------- GEMM: C[M,1024](TC) = A[M,1024](bf16) @ W[1024,1024]^T ---
// 2-phase pipeline: BMx128 tile, BK=32, 4 waves (2x2), linear LDS [rows][32],
// global_load_lds(16B), double-buffered: stage tile t+1 into buf^1 BEFORE
// computing tile t; the single end-of-step __syncthreads (vmcnt(0) drain)
// lands after ~300cy of ds_read+MFMA, so the prefetch latency is hidden.
// XCD-chunked bijective swizzle keeps each A-panel's 8 n-blocks on one XCD.
template <int BM, int NBY, int NBZ, typename TC>
__global__ __launch_bounds__(256, (BM == 128) ? 3 : 2) void gemm_bt_lds(
    const bf16* __restrict__ A0, const bf16* __restrict__ A1, const bf16* __restrict__ A2,
    const bf16* __restrict__ W, TC* __restrict__ C0, TC* __restrict__ C1, TC* __restrict__ C2,
    float scale0) {
  constexpr int K = 1024, N = 1024;
  constexpr int MT = BM / 32;        // m-fragments per wave
  constexpr int NB = 8 * NBY * NBZ;  // total blocks (divisible by 8)
  __shared__ __align__(16) bf16 As[2][BM * 32];
  __shared__ __align__(16) bf16 Bs[2][128 * 32];

  // bijective XCD-chunked swizzle: hw-linear id -> logical id
  const int lin = blockIdx.x + 8 * (blockIdx.y + NBY * blockIdx.z);
  const int l = (lin & 7) * (NB / 8) + (lin >> 3);
  const int lx = l & 7;
  const int lyz = l >> 3;
  const int ly = lyz % NBY;
  const int lz = lyz / NBY;

  const bf16* A = (lz == 0) ? A0 : (lz == 1) ? A1 : A2;
  TC* C = (lz == 0) ? C0 : (lz == 1) ? C1 : C2;
  const float sc = (lz == 0) ? scale0 : 1.0f;

  const int tid = threadIdx.x;
  const int lane = tid & 63;
  const int wv = tid >> 6;
  const int wm = wv >> 1, wn = wv & 1;
  const int lrow = lane & 15, quad = lane >> 4;
  const int m0 = ly * BM, n0 = lx * 128;

  // staging: thread t covers row (t>>2) of a 64-row stripe, 8 bf16 at (t&3)*8.
  // LDS offset = t*16 bytes -> wave-uniform base + lane*16 (gload_lds law).
  const int r0 = tid >> 2, c0 = (tid & 3) * 8;
  const bf16* pa0 = A + (size_t)(m0 + r0) * K + c0;
  const bf16* pb0 = W + (size_t)(n0 + r0) * K + c0;
  const bf16* pb1 = W + (size_t)(n0 + 64 + r0) * K + c0;
  const bf16* pa1 = nullptr;
  if constexpr (BM == 128) pa1 = A + (size_t)(m0 + 64 + r0) * K + c0;

  const f32x4 fz = {0.f, 0.f, 0.f, 0.f};
  f32x4 acc[MT][4];
#pragma unroll
  for (int i = 0; i < MT; ++i)
#pragma unroll
    for (int j = 0; j < 4; ++j) acc[i][j] = fz;

  // prologue: stage tile 0 into buffer 0
  gload16(pa0, &As[0][tid * 8]);
  if constexpr (BM == 128) gload16(pa1, &As[0][2048 + tid * 8]);
  gload16(pb0, &Bs[0][tid * 8]);
  gload16(pb1, &Bs[0][2048 + tid * 8]);
  __syncthreads();  // vmcnt(0): tile 0 resident

  for (int t = 0; t < K / 32; ++t) {
    const int cur = t & 1;
    if (t + 1 < K / 32) {  // issue next-tile prefetch into the other buffer
      const int k1 = (t + 1) * 32;
      gload16(pa0 + k1, &As[cur ^ 1][tid * 8]);
      if constexpr (BM == 128) gload16(pa1 + k1, &As[cur ^ 1][2048 + tid * 8]);
      gload16(pb0 + k1, &Bs[cur ^ 1][tid * 8]);
      gload16(pb1 + k1, &Bs[cur ^ 1][2048 + tid * 8]);
    }
    bf16x8 af[MT], bfr[4];
#pragma unroll
    for (int mt = 0; mt < MT; ++mt)
      af[mt] = *(const bf16x8*)(&As[cur][(wm * (BM / 2) + mt * 16 + lrow) * 32 + quad * 8]);
#pragma unroll
    for (int nt = 0; nt < 4; ++nt)
      bfr[nt] = *(const bf16x8*)(&Bs[cur][(wn * 64 + nt * 16 + lrow) * 32 + quad * 8]);
#pragma unroll
    for (int mt = 0; mt < MT; ++mt)
#pragma unroll
      for (int nt = 0; nt < 4; ++nt) acc[mt][nt] = MFMA16(af[mt], bfr[nt], acc[mt][nt]);
    __syncthreads();  // drains this step's prefetch (issued ~300cy ago) + ds reads
  }

#pragma unroll
  for (int mt = 0; mt < MT; ++mt) {
    const int gm = m0 + wm * (BM / 2) + mt * 16 + quad * 4;
#pragma unroll
    for (int nt = 0; nt < 4; ++nt) {
      const int gn = n0 + wn * 64 + nt * 16 + lrow;
#pragma unroll
      for (int r = 0; r < 4; ++r) C[(size_t)(gm + r) * N + gn] = (TC)(acc[mt][nt][r] * sc);
    }
  }
}

// ---------------- flash attention, transposed-S form ------------------------
// BQ=128/block (4 waves x 32 q-rows), K-tiles of 64, max-free softmax.
// S^T = K·Q^T: per-lane P = 4 consecutive keys at one q-row -> b64 stores.
// Double-buffered K (Qs reused as K buffer 1) + separate V buffers at stride
// LV=66 (b32 transpose-stores: bank = 2*vn2+... -> 2-way, free; stride 72 was
// 8-way). Mask bitwords prefetched one tile ahead.
__global__ __launch_bounds__(256, 2) void attn_kernel(const bf16* __restrict__ Qg,
                                                      const bf16* __restrict__ Kg,
                                                      const bf16* __restrict__ Vg,
                                                      const unsigned* __restrict__ bits,
                                                      bf16* __restrict__ Y) {
  constexpr int LQ = 72;
  constexpr int LV = 66;
  __shared__ bf16 Qs[128 * LQ];  // after qf extraction: K buffer 1 (rows 0-63)
  __shared__ bf16 Ks[64 * LQ];
  __shared__ bf16 Vt0[64 * LV];
  __shared__ bf16 Vt1[64 * LV];
  __shared__ bf16 Ps[4][32 * LQ];

  const int tid = threadIdx.x;
  const int lane = tid & 63;
  const int wv = tid >> 6;
  const int lrow = lane & 15, quad = lane >> 4;
  const int bh = blockIdx.y;
  const int b = bh >> 4, h = bh & 15;
  const int q0 = blockIdx.x * 128;

  const bf16* Qh = Qg + (size_t)bh * (SEQ * DK);
  const bf16* Kh = Kg + (size_t)bh * (SEQ * DK);
  const bf16* Vh = Vg + (size_t)bh * (SEQ * DK);

  // ---- stage Q tile (128x64, pre-scaled by QSCALE) ----
#pragma unroll
  for (int i = 0; i < 4; ++i) {
    int s = tid + i * 256;
    int row = s >> 3, c8 = (s & 7) * 8;
    *(uint4*)(&Qs[row * LQ + c8]) = *(const uint4*)(Qh + (size_t)(q0 + row) * DK + c8);
  }

  // ---- K/V prefetch-register plumbing ----
  const int krow = tid >> 3;  // 0..31 (second stripe: +32)
  const int kc8 = (tid & 7) * 8;
  const bf16* pk0 = Kh + (size_t)krow * DK + kc8;
  const bf16* pk1 = Kh + (size_t)(krow + 32) * DK + kc8;
  const int vn2 = tid & 31;   // dk-pair index
  const int vk2b = tid >> 5;  // key-pair base (k2 = vk2b + i*8)
  const bf16* pv0 = Vh + (size_t)(vk2b + 0) * 2 * DK + vn2 * 2;
  const bf16* pv1 = Vh + (size_t)(vk2b + 8) * 2 * DK + vn2 * 2;
  const bf16* pv2 = Vh + (size_t)(vk2b + 16) * 2 * DK + vn2 * 2;
  const bf16* pv3 = Vh + (size_t)(vk2b + 24) * 2 * DK + vn2 * 2;

  uint4 kr0, kr1;
  uint32_t va[4], vb[4];

  // tile 0 -> buffer 0 (Ks/Vt0; independent of Qs)
  kr0 = *(const uint4*)(pk0);
  kr1 = *(const uint4*)(pk1);
  va[0] = *(const uint32_t*)(pv0);
  vb[0] = *(const uint32_t*)(pv0 + DK);
  va[1] = *(const uint32_t*)(pv1);
  vb[1] = *(const uint32_t*)(pv1 + DK);
  va[2] = *(const uint32_t*)(pv2);
  vb[2] = *(const uint32_t*)(pv2 + DK);
  va[3] = *(const uint32_t*)(pv3);
  vb[3] = *(const uint32_t*)(pv3 + DK);
  *(uint4*)(&Ks[krow * LQ + kc8]) = kr0;
  *(uint4*)(&Ks[(krow + 32) * LQ + kc8]) = kr1;
#pragma unroll
  for (int i = 0; i < 4; ++i) {
    uint32_t t0 = (va[i] & 0xffffu) | (vb[i] << 16);
    uint32_t t1 = (va[i] >> 16) | (vb[i] & 0xffff0000u);
    *(uint32_t*)(&Vt0[(vn2 * 2) * LV + (vk2b + i * 8) * 2]) = t0;
    *(uint32_t*)(&Vt0[(vn2 * 2 + 1) * LV + (vk2b + i * 8) * 2]) = t1;
  }
  __syncthreads();  // Q + tile0 staged

  bf16x8 qf[2][2];  // B-frag for S^T: [q-row tile][ks]
#pragma unroll
  for (int nt = 0; nt < 2; ++nt)
#pragma unroll
    for (int ks = 0; ks < 2; ++ks)
      qf[nt][ks] = *(const bf16x8*)(&Qs[(wv * 32 + nt * 16 + lrow) * LQ + ks * 32 + quad * 8]);
  __syncthreads();  // all qf reads done -> Qs reusable as K buffer 1

  const f32x4 fz = {0.f, 0.f, 0.f, 0.f};
  f32x4 of_t[4][2];  // O^T: [dk-tile][q-row-tile]
#pragma unroll
  for (int i = 0; i < 4; ++i)
#pragma unroll
    for (int j = 0; j < 2; ++j) of_t[i][j] = fz;
  float lsum[2] = {0.f, 0.f};  // per-lane partial row sums (q-row nt*16+lrow)

  const unsigned* bitrow = bits + (size_t)b * SEQ * (SEQ / 32);

  // mask words for tile 0 (prefetched; subsequent tiles load one tile ahead)
  uint2 mwn[2];
#pragma unroll
  for (int nt = 0; nt < 2; ++nt) {
    int row = q0 + wv * 32 + nt * 16 + lrow;
    mwn[nt] = *(const uint2*)(bitrow + (size_t)row * (SEQ / 32));
  }

  for (int kt = 0; kt < 32; ++kt) {
    const int cur = kt & 1;
    bf16* kb = cur ? Qs : Ks;
    bf16* vbuf = cur ? Vt1 : Vt0;
    // prefetch next tile (global; overlaps the whole compute body)
    uint2 mwn_n[2];
    if (kt + 1 < 32) {
      const size_t adv = (size_t)(kt + 1) * 64 * DK;
      kr0 = *(const uint4*)(pk0 + adv);
      kr1 = *(const uint4*)(pk1 + adv);
      va[0] = *(const uint32_t*)(pv0 + adv);
      vb[0] = *(const uint32_t*)(pv0 + adv + DK);
      va[1] = *(const uint32_t*)(pv1 + adv);
      vb[1] = *(const uint32_t*)(pv1 + adv + DK);
      va[2] = *(const uint32_t*)(pv2 + adv);
      vb[2] = *(const uint32_t*)(pv2 + adv + DK);
      va[3] = *(const uint32_t*)(pv3 + adv);
      vb[3] = *(const uint32_t*)(pv3 + adv + DK);
#pragma unroll
      for (int nt = 0; nt < 2; ++nt) {
        int row = q0 + wv * 32 + nt * 16 + lrow;
        mwn_n[nt] = *(const uint2*)(bitrow + (size_t)row * (SEQ / 32) + (kt + 1) * 2);
      }
    }

    // ---- S^T = K @ Q^T (A = K-frag, B = Q-frag) ----
    f32x4 st[4][2];
#pragma unroll
    for (int mt = 0; mt < 4; ++mt)
#pragma unroll
      for (int nt = 0; nt < 2; ++nt) st[mt][nt] = fz;
#pragma unroll
    for (int ks = 0; ks < 2; ++ks) {
#pragma unroll
      for (int mt = 0; mt < 4; ++mt) {
        bf16x8 kfv = *(const bf16x8*)(kb + (mt * 16 + lrow) * LQ + ks * 32 + quad * 8);
#pragma unroll
        for (int nt = 0; nt < 2; ++nt) st[mt][nt] = MFMA16(kfv, qf[nt][ks], st[mt][nt]);
      }
    }

    // ---- max-free softmax; packed b64 P stores ----
    // lane's values: q-row = nt*16+lrow, keys = mt*16+quad*4+{0..3}
#pragma unroll
    for (int nt = 0; nt < 2; ++nt) {
      uint32_t ux = mwn[nt].x >> (quad * 4);
      uint32_t uy = mwn[nt].y >> (quad * 4);
      float psum = 0.f;
#pragma unroll
      for (int mt = 0; mt < 4; ++mt) {
        uint32_t u = (mt & 2) ? uy : ux;
        int sh = (mt & 1) << 4;
        bf16x4 pk;
#pragma unroll
        for (int r = 0; r < 4; ++r) {
          float p = EXP2(st[mt][nt][r]);
          p = ((u >> (sh + r)) & 1u) ? p : 0.f;
          psum += p;
          pk[r] = (bf16)p;
        }
        *(bf16x4*)(&Ps[wv][(nt * 16 + lrow) * LQ + mt * 16 + quad * 4]) = pk;
      }
      lsum[nt] += psum;
    }

    // ---- O^T += V^T @ P^T : A = Vt-frag, B = P-frag (both b128) ----
#pragma unroll
    for (int ks = 0; ks < 2; ++ks) {
      bf16x8 avf[4], bpf[2];
#pragma unroll
      for (int dkt = 0; dkt < 4; ++dkt)
        avf[dkt] = *(const bf16x8*)(vbuf + (dkt * 16 + lrow) * LV + ks * 32 + quad * 8);
#pragma unroll
      for (int rt = 0; rt < 2; ++rt)
        bpf[rt] = *(const bf16x8*)(&Ps[wv][(rt * 16 + lrow) * LQ + ks * 32 + quad * 8]);
#pragma unroll
      for (int dkt = 0; dkt < 4; ++dkt)
#pragma unroll
        for (int rt = 0; rt < 2; ++rt) of_t[dkt][rt] = MFMA16(avf[dkt], bpf[rt], of_t[dkt][rt]);
    }

    // stage next tile into the other buffer
    if (kt + 1 < 32) {
      bf16* kbn = cur ? Ks : Qs;
      bf16* vbn = cur ? Vt0 : Vt1;
      *(uint4*)(kbn + krow * LQ + kc8) = kr0;
      *(uint4*)(kbn + (krow + 32) * LQ + kc8) = kr1;
#pragma unroll
      for (int i = 0; i < 4; ++i) {
        uint32_t t0 = (va[i] & 0xffffu) | (vb[i] << 16);
        uint32_t t1 = (va[i] >> 16) | (vb[i] & 0xffff0000u);
        *(uint32_t*)(vbn + (vn2 * 2) * LV + (vk2b + i * 8) * 2) = t0;
        *(uint32_t*)(vbn + (vn2 * 2 + 1) * LV + (vk2b + i * 8) * 2) = t1;
      }
      mwn[0] = mwn_n[0];
      mwn[1] = mwn_n[1];
    }
    __syncthreads();  // single barrier per tile
  }

  // ---- row-sum: reduce per-lane partials across quads (2 shuffles) ----
  float linv[2];
#pragma unroll
  for (int nt = 0; nt < 2; ++nt) {
    float v = lsum[nt];
    v += __shfl_xor(v, 16);
    v += __shfl_xor(v, 32);
    linv[nt] = 1.0f / fmaxf(v, 1e-20f);
  }

  // ---- epilogue: O^T C-layout col = q-row (lrow), row = dk (quad*4+j) ----
#pragma unroll
  for (int dkt = 0; dkt < 4; ++dkt)
#pragma unroll
    for (int rt = 0; rt < 2; ++rt) {
      bf16x4 o;
#pragma unroll
      for (int j = 0; j < 4; ++j) o[j] = (bf16)(of_t[dkt][rt][j] * linv[rt]);
      const int row = q0 + wv * 32 + rt * 16 + lrow;
      *(bf16x4*)(&Y[((size_t)b * SEQ + row) * DIM + h * 64 + dkt * 16 + quad * 4]) = o;
    }
}

// ---------------------------------------------------------------------------
extern "C" void kernel_launch(void* const* d_in, const int* in_sizes, int n_in,
                              void* d_out, int out_size, void* d_ws, size_t ws_size,
                              hipStream_t stream) {
  const float* query = (const float*)d_in[0];
  const float* key = (const float*)d_in[1];
  const float* value = (const float*)d_in[2];
  const float* Wqkv = (const float*)d_in[3];
  const float* Wout = (const float*)d_in[4];
  const int* mask = (const int*)d_in[5];
  float* out = (float*)d_out;

  // workspace map (53 MB total; y aliases dead qin region)
  char* ws = (char*)d_ws;
  bf16* qin = (bf16*)(ws);             //  8 MB  bf16 query (dead after QKV GEMM)
  bf16* kin = (bf16*)(ws + 8388608);   //  8 MB  bf16 key
  bf16* vin = (bf16*)(ws + 16777216);  //  8 MB  bf16 value
  bf16* Wq = (bf16*)(ws + 25165824);   //  2 MB  bf16 Wqkv
  bf16* Wo = (bf16*)(ws + 27262976);   //  2 MB  bf16 Wout
  bf16* q = (bf16*)(ws + 29360128);    //  8 MB  projected q (pre-scaled)
  bf16* k = (bf16*)(ws + 37748736);    //  8 MB
  bf16* v = (bf16*)(ws + 46137344);    //  8 MB
  bf16* y = (bf16*)(ws);               //  8 MB  attn out (aliases qin)
  unsigned long long* bits64 = (unsigned long long*)(ws + 54525952);  // 1 MB

  // 1) mask -> bits
  mask_bits_kernel<<<(BATCH * SEQ * SEQ) / 256, 256, 0, stream>>>(mask, bits64);

  // 2) fp32 -> bf16 one-shot convert (q/k/v activations + both weights)
  cvt_bf16_kernel<<<dim3(256, 5), 256, 0, stream>>>(query, key, value, Wqkv, Wout,
                                                    qin, kin, vin, Wq, Wo);

  // 3) fused QKV projection (q scaled by QSCALE in epilogue, z==0 only)
  gemm_bt_lds<128, 32, 3, bf16>
      <<<dim3(8, 32, 3), 256, 0, stream>>>(qin, kin, vin, Wq, q, k, v, QSCALE);

  // 4) flash attention (16 q-tiles x 32 heads)
  attn_kernel<<<dim3(16, 32), 256, 0, stream>>>(q, k, v, (const unsigned*)bits64, y);

  // 5) output projection -> fp32 out; BM=64 -> 512 blocks (2 blocks/CU)
  gemm_bt_lds<64, 64, 1, float>
      <<<dim3(8, 64, 1), 256, 0, stream>>>(y, y, y, Wo, out, out, out, 1.0f);
}

// Round 3
// 253.057 us; speedup vs baseline: 1.1320x; 1.1320x over previous
//
#include <hip/hip_runtime.h>
#include <stdint.h>

// ---------------------------------------------------------------------------
// MultiHeadedAttention (B=2,S=2048,D=1024,H=16,DK=64)
//   INPUTS fp32 (query,key,value,Wqkv,Wout) + int32 mask; OUTPUT fp32.
// R10:
//   * attn: exact R8 revert (R9's LV=66 V-stride unbalanced the PV read
//     banks -> 77->111us regression; store conflicts were overlapped anyway).
//   * GEMM: XOR-swizzled LDS (rule #21: linear gload_lds dest + pre-swizzled
//     GLOBAL source col-block + swizzled ds_read block). Kills the 8-way
//     bank conflict on every fragment ds_read_b128 (starts were
//     16(r&1)+4quad = 8 groups x 8 lanes; now 2-way = free).
//   * GEMM keeps R9 2-phase double-buffer (neutral but pairs with the
//     conflict fix: drain hidden by occupancy -> LDS-read is critical path).
// ---------------------------------------------------------------------------

typedef __bf16 bf16;
typedef __bf16 bf16x8 __attribute__((ext_vector_type(8)));
typedef __bf16 bf16x4 __attribute__((ext_vector_type(4)));
typedef float f32x4 __attribute__((ext_vector_type(4)));

#define MFMA16(a, b, c) __builtin_amdgcn_mfma_f32_16x16x32_bf16((a), (b), (c), 0, 0, 0)
#define EXP2(x) __builtin_amdgcn_exp2f(x)

static constexpr int BATCH = 2;
static constexpr int SEQ = 2048;
static constexpr int DIM = 1024;
static constexpr int DK = 64;
// q is pre-scaled by 1/sqrt(DK) * log2(e) in the QKV GEMM epilogue (z==0)
static constexpr float QSCALE = 0.125f * 1.44269504088896340736f;

// ---- async global->LDS, 16 B per lane -------------------------------------
__device__ inline void gload16(const void* g, void* l) {
  __builtin_amdgcn_global_load_lds((const __attribute__((address_space(1))) void*)g,
                                   (__attribute__((address_space(3))) void*)l, 16, 0, 0);
}

// ---------------- mask (int32 0/1) -> bitmask, 1 bit per element -----------
__global__ __launch_bounds__(256) void mask_bits_kernel(const int* __restrict__ mask,
                                                        unsigned long long* __restrict__ bits) {
  int idx = blockIdx.x * 256 + threadIdx.x;  // grid covers exactly B*S*S
  int m = mask[idx];
  unsigned long long bal = __ballot(m != 0);
  if ((threadIdx.x & 63) == 0) bits[idx >> 6] = bal;
}

// ---------------- fp32 -> bf16 convert (5 tensors, one launch) -------------
__global__ __launch_bounds__(256) void cvt_bf16_kernel(const float* __restrict__ s0,
                                                       const float* __restrict__ s1,
                                                       const float* __restrict__ s2,
                                                       const float* __restrict__ s3,
                                                       const float* __restrict__ s4,
                                                       bf16* __restrict__ d0, bf16* __restrict__ d1,
                                                       bf16* __restrict__ d2, bf16* __restrict__ d3,
                                                       bf16* __restrict__ d4) {
  const int y = blockIdx.y;
  const float* s = (y == 0) ? s0 : (y == 1) ? s1 : (y == 2) ? s2 : (y == 3) ? s3 : s4;
  bf16* d = (y == 0) ? d0 : (y == 1) ? d1 : (y == 2) ? d2 : (y == 3) ? d3 : d4;
  const int n8 = (y < 3) ? (BATCH * SEQ * DIM / 8) : (DIM * DIM / 8);
  for (int i = blockIdx.x * 256 + threadIdx.x; i < n8; i += gridDim.x * 256) {
    const float4 a = ((const float4*)s)[2 * i];
    const float4 b = ((const float4*)s)[2 * i + 1];
    bf16x8 v;
    v[0] = (bf16)a.x;
    v[1] = (bf16)a.y;
    v[2] = (bf16)a.z;
    v[3] = (bf16)a.w;
    v[4] = (bf16)b.x;
    v[5] = (bf16)b.y;
    v[6] = (bf16)b.z;
    v[7] = (bf16)b.w;
    ((bf16x8*)d)[i] = v;
  }
}

// ---------------- GEMM: C[M,1024](TC) = A[M,1024](bf16) @ W[1024,1024]^T ---
// 2-phase pipeline, BMx128 tile, BK=32, 4 waves (2x2), XOR-swizzled LDS:
//   LDS row r, 16B-block j holds GLOBAL 16B-block j ^ ((r>>1)&3).
//   - staging: gload_lds dest linear (tid*16B); global source col-block
//     pre-permuted (same 64B segment -> coalescing unchanged).
//   - fragment read for row r, k-block quad: LDS block quad ^ ((r>>1)&3)
//     -> bank starts cover all 8 4-bank groups x 2 lanes = 2-way (free),
//     was 8-way (16(r&1)+4quad).
// XCD-chunked bijective swizzle keeps each A-panel's 8 n-blocks on one XCD.
template <int BM, int NBY, int NBZ, typename TC>
__global__ __launch_bounds__(256, (BM == 128) ? 3 : 2) void gemm_bt_lds(
    const bf16* __restrict__ A0, const bf16* __restrict__ A1, const bf16* __restrict__ A2,
    const bf16* __restrict__ W, TC* __restrict__ C0, TC* __restrict__ C1, TC* __restrict__ C2,
    float scale0) {
  constexpr int K = 1024, N = 1024;
  constexpr int MT = BM / 32;        // m-fragments per wave
  constexpr int NB = 8 * NBY * NBZ;  // total blocks (divisible by 8)
  __shared__ __align__(16) bf16 As[2][BM * 32];
  __shared__ __align__(16) bf16 Bs[2][128 * 32];

  // bijective XCD-chunked swizzle: hw-linear id -> logical id
  const int lin = blockIdx.x + 8 * (blockIdx.y + NBY * blockIdx.z);
  const int l = (lin & 7) * (NB / 8) + (lin >> 3);
  const int lx = l & 7;
  const int lyz = l >> 3;
  const int ly = lyz % NBY;
  const int lz = lyz / NBY;

  const bf16* A = (lz == 0) ? A0 : (lz == 1) ? A1 : A2;
  TC* C = (lz == 0) ? C0 : (lz == 1) ? C1 : C2;
  const float sc = (lz == 0) ? scale0 : 1.0f;

  const int tid = threadIdx.x;
  const int lane = tid & 63;
  const int wv = tid >> 6;
  const int wm = wv >> 1, wn = wv & 1;
  const int lrow = lane & 15, quad = lane >> 4;
  const int m0 = ly * BM, n0 = lx * 128;

  // staging: thread t covers row (t>>2); global 16B-block = (t&3) ^ ((r>>1)&3)
  // (rows r and r+64 share the same swizzle since 64>>1 = 32 === 0 mod 4).
  const int r0 = tid >> 2;
  const int c0 = (((tid & 3) ^ ((r0 >> 1) & 3)) * 8);
  const bf16* pa0 = A + (size_t)(m0 + r0) * K + c0;
  const bf16* pb0 = W + (size_t)(n0 + r0) * K + c0;
  const bf16* pb1 = W + (size_t)(n0 + 64 + r0) * K + c0;
  const bf16* pa1 = nullptr;
  if constexpr (BM == 128) pa1 = A + (size_t)(m0 + 64 + r0) * K + c0;

  const f32x4 fz = {0.f, 0.f, 0.f, 0.f};
  f32x4 acc[MT][4];
#pragma unroll
  for (int i = 0; i < MT; ++i)
#pragma unroll
    for (int j = 0; j < 4; ++j) acc[i][j] = fz;

  // fragment-read swizzle: row = ...16*mt + lrow (16,64 === 0 mod 4 after >>1)
  const int sw = (lrow >> 1) & 3;
  const int rb = (quad ^ sw) * 8;  // swizzled 16B-block offset (elements)

  // prologue: stage tile 0 into buffer 0
  gload16(pa0, &As[0][tid * 8]);
  if constexpr (BM == 128) gload16(pa1, &As[0][2048 + tid * 8]);
  gload16(pb0, &Bs[0][tid * 8]);
  gload16(pb1, &Bs[0][2048 + tid * 8]);
  __syncthreads();  // vmcnt(0): tile 0 resident

  for (int t = 0; t < K / 32; ++t) {
    const int cur = t & 1;
    if (t + 1 < K / 32) {  // issue next-tile prefetch into the other buffer
      const int k1 = (t + 1) * 32;
      gload16(pa0 + k1, &As[cur ^ 1][tid * 8]);
      if constexpr (BM == 128) gload16(pa1 + k1, &As[cur ^ 1][2048 + tid * 8]);
      gload16(pb0 + k1, &Bs[cur ^ 1][tid * 8]);
      gload16(pb1 + k1, &Bs[cur ^ 1][2048 + tid * 8]);
    }
    bf16x8 af[MT], bfr[4];
#pragma unroll
    for (int mt = 0; mt < MT; ++mt)
      af[mt] = *(const bf16x8*)(&As[cur][(wm * (BM / 2) + mt * 16 + lrow) * 32 + rb]);
#pragma unroll
    for (int nt = 0; nt < 4; ++nt)
      bfr[nt] = *(const bf16x8*)(&Bs[cur][(wn * 64 + nt * 16 + lrow) * 32 + rb]);
#pragma unroll
    for (int mt = 0; mt < MT; ++mt)
#pragma unroll
      for (int nt = 0; nt < 4; ++nt) acc[mt][nt] = MFMA16(af[mt], bfr[nt], acc[mt][nt]);
    __syncthreads();  // drains this step's prefetch + all ds reads
  }

#pragma unroll
  for (int mt = 0; mt < MT; ++mt) {
    const int gm = m0 + wm * (BM / 2) + mt * 16 + quad * 4;
#pragma unroll
    for (int nt = 0; nt < 4; ++nt) {
      const int gn = n0 + wn * 64 + nt * 16 + lrow;
#pragma unroll
      for (int r = 0; r < 4; ++r) C[(size_t)(gm + r) * N + gn] = (TC)(acc[mt][nt][r] * sc);
    }
  }
}

// ---------------- flash attention, transposed-S form (R8 exact) ------------
// BQ=128/block (4 waves x 32 q-rows), K-tiles of 64, max-free softmax.
// S^T = K·Q^T: per-lane P = 4 consecutive keys at one q-row -> b64 stores.
// Double-buffered K/V LDS (Qs reused as buffer 1), one barrier per tile.
__global__ __launch_bounds__(256, 2) void attn_kernel(const bf16* __restrict__ Qg,
                                                      const bf16* __restrict__ Kg,
                                                      const bf16* __restrict__ Vg,
                                                      const unsigned* __restrict__ bits,
                                                      bf16* __restrict__ Y) {
  constexpr int LQ = 72;
  __shared__ bf16 Qs[128 * LQ];  // after qf extraction: K/V buffer 1
  __shared__ bf16 Ks[64 * LQ];
  __shared__ bf16 Vts[64 * LQ];
  __shared__ bf16 Ps[4][32 * LQ];

  const int tid = threadIdx.x;
  const int lane = tid & 63;
  const int wv = tid >> 6;
  const int lrow = lane & 15, quad = lane >> 4;
  const int bh = blockIdx.y;
  const int b = bh >> 4, h = bh & 15;
  const int q0 = blockIdx.x * 128;

  const bf16* Qh = Qg + (size_t)bh * (SEQ * DK);
  const bf16* Kh = Kg + (size_t)bh * (SEQ * DK);
  const bf16* Vh = Vg + (size_t)bh * (SEQ * DK);

  // ---- stage Q tile (128x64, pre-scaled by QSCALE) ----
#pragma unroll
  for (int i = 0; i < 4; ++i) {
    int s = tid + i * 256;
    int row = s >> 3, c8 = (s & 7) * 8;
    *(uint4*)(&Qs[row * LQ + c8]) = *(const uint4*)(Qh + (size_t)(q0 + row) * DK + c8);
  }

  // ---- K/V prefetch-register plumbing ----
  const int krow = tid >> 3;  // 0..31 (second stripe: +32)
  const int kc8 = (tid & 7) * 8;
  const bf16* pk0 = Kh + (size_t)krow * DK + kc8;
  const bf16* pk1 = Kh + (size_t)(krow + 32) * DK + kc8;
  const int vn2 = tid & 31;   // dk-pair index
  const int vk2b = tid >> 5;  // key-pair base (k2 = vk2b + i*8)
  const bf16* pv0 = Vh + (size_t)(vk2b + 0) * 2 * DK + vn2 * 2;
  const bf16* pv1 = Vh + (size_t)(vk2b + 8) * 2 * DK + vn2 * 2;
  const bf16* pv2 = Vh + (size_t)(vk2b + 16) * 2 * DK + vn2 * 2;
  const bf16* pv3 = Vh + (size_t)(vk2b + 24) * 2 * DK + vn2 * 2;

  uint4 kr0, kr1;
  uint32_t va[4], vb[4];

  // tile 0 -> buffer 0 (Ks/Vts; independent of Qs)
  kr0 = *(const uint4*)(pk0);
  kr1 = *(const uint4*)(pk1);
  va[0] = *(const uint32_t*)(pv0);
  vb[0] = *(const uint32_t*)(pv0 + DK);
  va[1] = *(const uint32_t*)(pv1);
  vb[1] = *(const uint32_t*)(pv1 + DK);
  va[2] = *(const uint32_t*)(pv2);
  vb[2] = *(const uint32_t*)(pv2 + DK);
  va[3] = *(const uint32_t*)(pv3);
  vb[3] = *(const uint32_t*)(pv3 + DK);
  *(uint4*)(&Ks[krow * LQ + kc8]) = kr0;
  *(uint4*)(&Ks[(krow + 32) * LQ + kc8]) = kr1;
#pragma unroll
  for (int i = 0; i < 4; ++i) {
    uint32_t t0 = (va[i] & 0xffffu) | (vb[i] << 16);
    uint32_t t1 = (va[i] >> 16) | (vb[i] & 0xffff0000u);
    *(uint32_t*)(&Vts[(vn2 * 2) * LQ + (vk2b + i * 8) * 2]) = t0;
    *(uint32_t*)(&Vts[(vn2 * 2 + 1) * LQ + (vk2b + i * 8) * 2]) = t1;
  }
  __syncthreads();  // Q + tile0 staged

  bf16x8 qf[2][2];  // B-frag for S^T: [q-row tile][ks]
#pragma unroll
  for (int nt = 0; nt < 2; ++nt)
#pragma unroll
    for (int ks = 0; ks < 2; ++ks)
      qf[nt][ks] = *(const bf16x8*)(&Qs[(wv * 32 + nt * 16 + lrow) * LQ + ks * 32 + quad * 8]);
  __syncthreads();  // all qf reads done -> Qs reusable as buffer 1

  const f32x4 fz = {0.f, 0.f, 0.f, 0.f};
  f32x4 of_t[4][2];  // O^T: [dk-tile][q-row-tile]
#pragma unroll
  for (int i = 0; i < 4; ++i)
#pragma unroll
    for (int j = 0; j < 2; ++j) of_t[i][j] = fz;
  float lsum[2] = {0.f, 0.f};  // per-lane partial row sums (q-row nt*16+lrow)

  const unsigned* bitrow = bits + (size_t)b * SEQ * (SEQ / 32);

  for (int kt = 0; kt < 32; ++kt) {
    const int cur = kt & 1;
    bf16* kb = cur ? Qs : Ks;
    bf16* vbuf = cur ? (Qs + 64 * LQ) : Vts;
    // prefetch next tile (global; overlaps the whole compute body)
    if (kt + 1 < 32) {
      const size_t adv = (size_t)(kt + 1) * 64 * DK;
      kr0 = *(const uint4*)(pk0 + adv);
      kr1 = *(const uint4*)(pk1 + adv);
      va[0] = *(const uint32_t*)(pv0 + adv);
      vb[0] = *(const uint32_t*)(pv0 + adv + DK);
      va[1] = *(const uint32_t*)(pv1 + adv);
      vb[1] = *(const uint32_t*)(pv1 + adv + DK);
      va[2] = *(const uint32_t*)(pv2 + adv);
      vb[2] = *(const uint32_t*)(pv2 + adv + DK);
      va[3] = *(const uint32_t*)(pv3 + adv);
      vb[3] = *(const uint32_t*)(pv3 + adv + DK);
    }
    // mask: one 64-bit word per q-row covers this tile's 64 keys
    uint2 mwn[2];
#pragma unroll
    for (int nt = 0; nt < 2; ++nt) {
      int row = q0 + wv * 32 + nt * 16 + lrow;
      mwn[nt] = *(const uint2*)(bitrow + (size_t)row * (SEQ / 32) + kt * 2);
    }

    // ---- S^T = K @ Q^T (A = K-frag, B = Q-frag) ----
    f32x4 st[4][2];
#pragma unroll
    for (int mt = 0; mt < 4; ++mt)
#pragma unroll
      for (int nt = 0; nt < 2; ++nt) st[mt][nt] = fz;
#pragma unroll
    for (int ks = 0; ks < 2; ++ks) {
#pragma unroll
      for (int mt = 0; mt < 4; ++mt) {
        bf16x8 kfv = *(const bf16x8*)(kb + (mt * 16 + lrow) * LQ + ks * 32 + quad * 8);
#pragma unroll
        for (int nt = 0; nt < 2; ++nt) st[mt][nt] = MFMA16(kfv, qf[nt][ks], st[mt][nt]);
      }
    }

    // ---- max-free softmax; packed b64 P stores ----
    // lane's values: q-row = nt*16+lrow, keys = mt*16+quad*4+{0..3}
#pragma unroll
    for (int nt = 0; nt < 2; ++nt) {
      uint32_t ux = mwn[nt].x >> (quad * 4);
      uint32_t uy = mwn[nt].y >> (quad * 4);
      float psum = 0.f;
#pragma unroll
      for (int mt = 0; mt < 4; ++mt) {
        uint32_t u = (mt & 2) ? uy : ux;
        int sh = (mt & 1) << 4;
        bf16x4 pk;
#pragma unroll
        for (int r = 0; r < 4; ++r) {
          float p = EXP2(st[mt][nt][r]);
          p = ((u >> (sh + r)) & 1u) ? p : 0.f;
          psum += p;
          pk[r] = (bf16)p;
        }
        *(bf16x4*)(&Ps[wv][(nt * 16 + lrow) * LQ + mt * 16 + quad * 4]) = pk;
      }
      lsum[nt] += psum;
    }

    // ---- O^T += V^T @ P^T : A = Vt-frag, B = P-frag (both b128) ----
#pragma unroll
    for (int ks = 0; ks < 2; ++ks) {
      bf16x8 avf[4], bpf[2];
#pragma unroll
      for (int dkt = 0; dkt < 4; ++dkt)
        avf[dkt] = *(const bf16x8*)(vbuf + (dkt * 16 + lrow) * LQ + ks * 32 + quad * 8);
#pragma unroll
      for (int rt = 0; rt < 2; ++rt)
        bpf[rt] = *(const bf16x8*)(&Ps[wv][(rt * 16 + lrow) * LQ + ks * 32 + quad * 8]);
#pragma unroll
      for (int dkt = 0; dkt < 4; ++dkt)
#pragma unroll
        for (int rt = 0; rt < 2; ++rt) of_t[dkt][rt] = MFMA16(avf[dkt], bpf[rt], of_t[dkt][rt]);
    }

    // stage next tile into the other buffer
    if (kt + 1 < 32) {
      bf16* kbn = cur ? Ks : Qs;
      bf16* vbn = cur ? Vts : (Qs + 64 * LQ);
      *(uint4*)(kbn + krow * LQ + kc8) = kr0;
      *(uint4*)(kbn + (krow + 32) * LQ + kc8) = kr1;
#pragma unroll
      for (int i = 0; i < 4; ++i) {
        uint32_t t0 = (va[i] & 0xffffu) | (vb[i] << 16);
        uint32_t t1 = (va[i] >> 16) | (vb[i] & 0xffff0000u);
        *(uint32_t*)(vbn + (vn2 * 2) * LQ + (vk2b + i * 8) * 2) = t0;
        *(uint32_t*)(vbn + (vn2 * 2 + 1) * LQ + (vk2b + i * 8) * 2) = t1;
      }
    }
    __syncthreads();  // single barrier per tile
  }

  // ---- row-sum: reduce per-lane partials across quads (2 shuffles) ----
  float linv[2];
#pragma unroll
  for (int nt = 0; nt < 2; ++nt) {
    float v = lsum[nt];
    v += __shfl_xor(v, 16);
    v += __shfl_xor(v, 32);
    linv[nt] = 1.0f / fmaxf(v, 1e-20f);
  }

  // ---- epilogue: O^T C-layout col = q-row (lrow), row = dk (quad*4+j) ----
#pragma unroll
  for (int dkt = 0; dkt < 4; ++dkt)
#pragma unroll
    for (int rt = 0; rt < 2; ++rt) {
      bf16x4 o;
#pragma unroll
      for (int j = 0; j < 4; ++j) o[j] = (bf16)(of_t[dkt][rt][j] * linv[rt]);
      const int row = q0 + wv * 32 + rt * 16 + lrow;
      *(bf16x4*)(&Y[((size_t)b * SEQ + row) * DIM + h * 64 + dkt * 16 + quad * 4]) = o;
    }
}

// ---------------------------------------------------------------------------
extern "C" void kernel_launch(void* const* d_in, const int* in_sizes, int n_in,
                              void* d_out, int out_size, void* d_ws, size_t ws_size,
                              hipStream_t stream) {
  const float* query = (const float*)d_in[0];
  const float* key = (const float*)d_in[1];
  const float* value = (const float*)d_in[2];
  const float* Wqkv = (const float*)d_in[3];
  const float* Wout = (const float*)d_in[4];
  const int* mask = (const int*)d_in[5];
  float* out = (float*)d_out;

  // workspace map (53 MB total; y aliases dead qin region)
  char* ws = (char*)d_ws;
  bf16* qin = (bf16*)(ws);             //  8 MB  bf16 query (dead after QKV GEMM)
  bf16* kin = (bf16*)(ws + 8388608);   //  8 MB  bf16 key
  bf16* vin = (bf16*)(ws + 16777216);  //  8 MB  bf16 value
  bf16* Wq = (bf16*)(ws + 25165824);   //  2 MB  bf16 Wqkv
  bf16* Wo = (bf16*)(ws + 27262976);   //  2 MB  bf16 Wout
  bf16* q = (bf16*)(ws + 29360128);    //  8 MB  projected q (pre-scaled)
  bf16* k = (bf16*)(ws + 37748736);    //  8 MB
  bf16* v = (bf16*)(ws + 46137344);    //  8 MB
  bf16* y = (bf16*)(ws);               //  8 MB  attn out (aliases qin)
  unsigned long long* bits64 = (unsigned long long*)(ws + 54525952);  // 1 MB

  // 1) mask -> bits
  mask_bits_kernel<<<(BATCH * SEQ * SEQ) / 256, 256, 0, stream>>>(mask, bits64);

  // 2) fp32 -> bf16 one-shot convert (q/k/v activations + both weights)
  cvt_bf16_kernel<<<dim3(256, 5), 256, 0, stream>>>(query, key, value, Wqkv, Wout,
                                                    qin, kin, vin, Wq, Wo);

  // 3) fused QKV projection (q scaled by QSCALE in epilogue, z==0 only)
  gemm_bt_lds<128, 32, 3, bf16>
      <<<dim3(8, 32, 3), 256, 0, stream>>>(qin, kin, vin, Wq, q, k, v, QSCALE);

  // 4) flash attention (16 q-tiles x 32 heads)
  attn_kernel<<<dim3(16, 32), 256, 0, stream>>>(q, k, v, (const unsigned*)bits64, y);

  // 5) output projection -> fp32 out; BM=64 -> 512 blocks (2 blocks/CU)
  gemm_bt_lds<64, 64, 1, float>
      <<<dim3(8, 64, 1), 256, 0, stream>>>(y, y, y, Wo, out, out, out, 1.0f);
}

// Round 4
// 248.693 us; speedup vs baseline: 1.1519x; 1.0175x over previous
//
#include <hip/hip_runtime.h>
#include <stdint.h>

// ---------------------------------------------------------------------------
// MultiHeadedAttention (B=2,S=2048,D=1024,H=16,DK=64)
//   INPUTS fp32 (query,key,value,Wqkv,Wout) + int32 mask; OUTPUT fp32.
// R11:
//   * cvt: grid 256->2048 blocks (was 1 block/CU / 4 waves/CU = latency-bound
//     at ~1 TB/s; now 1 elem/thread pure streaming). Main bet of the round.
//   * attn: s_setprio(1) around QK^T and PV MFMA clusters (T5, m191 regime:
//     independent blocks at different phases). Directly visible in top-5.
//   * GEMMs byte-identical to R10 (control).
// ---------------------------------------------------------------------------

typedef __bf16 bf16;
typedef __bf16 bf16x8 __attribute__((ext_vector_type(8)));
typedef __bf16 bf16x4 __attribute__((ext_vector_type(4)));
typedef float f32x4 __attribute__((ext_vector_type(4)));

#define MFMA16(a, b, c) __builtin_amdgcn_mfma_f32_16x16x32_bf16((a), (b), (c), 0, 0, 0)
#define EXP2(x) __builtin_amdgcn_exp2f(x)

static constexpr int BATCH = 2;
static constexpr int SEQ = 2048;
static constexpr int DIM = 1024;
static constexpr int DK = 64;
// q is pre-scaled by 1/sqrt(DK) * log2(e) in the QKV GEMM epilogue (z==0)
static constexpr float QSCALE = 0.125f * 1.44269504088896340736f;

// ---- async global->LDS, 16 B per lane -------------------------------------
__device__ inline void gload16(const void* g, void* l) {
  __builtin_amdgcn_global_load_lds((const __attribute__((address_space(1))) void*)g,
                                   (__attribute__((address_space(3))) void*)l, 16, 0, 0);
}

// ---------------- mask (int32 0/1) -> bitmask, 1 bit per element -----------
__global__ __launch_bounds__(256) void mask_bits_kernel(const int* __restrict__ mask,
                                                        unsigned long long* __restrict__ bits) {
  int idx = blockIdx.x * 256 + threadIdx.x;  // grid covers exactly B*S*S
  int m = mask[idx];
  unsigned long long bal = __ballot(m != 0);
  if ((threadIdx.x & 63) == 0) bits[idx >> 6] = bal;
}

// ---------------- fp32 -> bf16 convert (5 tensors, one launch) -------------
// grid 2048x5: activations = exactly 1 bf16x8 per thread (no loop), weights
// cover in the first 512 blocks' threads. Full-occupancy streaming.
__global__ __launch_bounds__(256) void cvt_bf16_kernel(const float* __restrict__ s0,
                                                       const float* __restrict__ s1,
                                                       const float* __restrict__ s2,
                                                       const float* __restrict__ s3,
                                                       const float* __restrict__ s4,
                                                       bf16* __restrict__ d0, bf16* __restrict__ d1,
                                                       bf16* __restrict__ d2, bf16* __restrict__ d3,
                                                       bf16* __restrict__ d4) {
  const int y = blockIdx.y;
  const float* s = (y == 0) ? s0 : (y == 1) ? s1 : (y == 2) ? s2 : (y == 3) ? s3 : s4;
  bf16* d = (y == 0) ? d0 : (y == 1) ? d1 : (y == 2) ? d2 : (y == 3) ? d3 : d4;
  const int n8 = (y < 3) ? (BATCH * SEQ * DIM / 8) : (DIM * DIM / 8);
  const int i = blockIdx.x * 256 + threadIdx.x;
  if (i < n8) {
    const float4 a = ((const float4*)s)[2 * i];
    const float4 b = ((const float4*)s)[2 * i + 1];
    bf16x8 v;
    v[0] = (bf16)a.x;
    v[1] = (bf16)a.y;
    v[2] = (bf16)a.z;
    v[3] = (bf16)a.w;
    v[4] = (bf16)b.x;
    v[5] = (bf16)b.y;
    v[6] = (bf16)b.z;
    v[7] = (bf16)b.w;
    ((bf16x8*)d)[i] = v;
  }
}

// ---------------- GEMM: C[M,1024](TC) = A[M,1024](bf16) @ W[1024,1024]^T ---
// 2-phase pipeline, BMx128 tile, BK=32, 4 waves (2x2), XOR-swizzled LDS
// (linear gload_lds dest + pre-swizzled GLOBAL source + swizzled ds_read).
// XCD-chunked bijective swizzle keeps each A-panel's 8 n-blocks on one XCD.
template <int BM, int NBY, int NBZ, typename TC>
__global__ __launch_bounds__(256, (BM == 128) ? 3 : 2) void gemm_bt_lds(
    const bf16* __restrict__ A0, const bf16* __restrict__ A1, const bf16* __restrict__ A2,
    const bf16* __restrict__ W, TC* __restrict__ C0, TC* __restrict__ C1, TC* __restrict__ C2,
    float scale0) {
  constexpr int K = 1024, N = 1024;
  constexpr int MT = BM / 32;        // m-fragments per wave
  constexpr int NB = 8 * NBY * NBZ;  // total blocks (divisible by 8)
  __shared__ __align__(16) bf16 As[2][BM * 32];
  __shared__ __align__(16) bf16 Bs[2][128 * 32];

  // bijective XCD-chunked swizzle: hw-linear id -> logical id
  const int lin = blockIdx.x + 8 * (blockIdx.y + NBY * blockIdx.z);
  const int l = (lin & 7) * (NB / 8) + (lin >> 3);
  const int lx = l & 7;
  const int lyz = l >> 3;
  const int ly = lyz % NBY;
  const int lz = lyz / NBY;

  const bf16* A = (lz == 0) ? A0 : (lz == 1) ? A1 : A2;
  TC* C = (lz == 0) ? C0 : (lz == 1) ? C1 : C2;
  const float sc = (lz == 0) ? scale0 : 1.0f;

  const int tid = threadIdx.x;
  const int lane = tid & 63;
  const int wv = tid >> 6;
  const int wm = wv >> 1, wn = wv & 1;
  const int lrow = lane & 15, quad = lane >> 4;
  const int m0 = ly * BM, n0 = lx * 128;

  // staging: thread t covers row (t>>2); global 16B-block = (t&3) ^ ((r>>1)&3)
  const int r0 = tid >> 2;
  const int c0 = (((tid & 3) ^ ((r0 >> 1) & 3)) * 8);
  const bf16* pa0 = A + (size_t)(m0 + r0) * K + c0;
  const bf16* pb0 = W + (size_t)(n0 + r0) * K + c0;
  const bf16* pb1 = W + (size_t)(n0 + 64 + r0) * K + c0;
  const bf16* pa1 = nullptr;
  if constexpr (BM == 128) pa1 = A + (size_t)(m0 + 64 + r0) * K + c0;

  const f32x4 fz = {0.f, 0.f, 0.f, 0.f};
  f32x4 acc[MT][4];
#pragma unroll
  for (int i = 0; i < MT; ++i)
#pragma unroll
    for (int j = 0; j < 4; ++j) acc[i][j] = fz;

  // fragment-read swizzle
  const int sw = (lrow >> 1) & 3;
  const int rb = (quad ^ sw) * 8;  // swizzled 16B-block offset (elements)

  // prologue: stage tile 0 into buffer 0
  gload16(pa0, &As[0][tid * 8]);
  if constexpr (BM == 128) gload16(pa1, &As[0][2048 + tid * 8]);
  gload16(pb0, &Bs[0][tid * 8]);
  gload16(pb1, &Bs[0][2048 + tid * 8]);
  __syncthreads();  // vmcnt(0): tile 0 resident

  for (int t = 0; t < K / 32; ++t) {
    const int cur = t & 1;
    if (t + 1 < K / 32) {  // issue next-tile prefetch into the other buffer
      const int k1 = (t + 1) * 32;
      gload16(pa0 + k1, &As[cur ^ 1][tid * 8]);
      if constexpr (BM == 128) gload16(pa1 + k1, &As[cur ^ 1][2048 + tid * 8]);
      gload16(pb0 + k1, &Bs[cur ^ 1][tid * 8]);
      gload16(pb1 + k1, &Bs[cur ^ 1][2048 + tid * 8]);
    }
    bf16x8 af[MT], bfr[4];
#pragma unroll
    for (int mt = 0; mt < MT; ++mt)
      af[mt] = *(const bf16x8*)(&As[cur][(wm * (BM / 2) + mt * 16 + lrow) * 32 + rb]);
#pragma unroll
    for (int nt = 0; nt < 4; ++nt)
      bfr[nt] = *(const bf16x8*)(&Bs[cur][(wn * 64 + nt * 16 + lrow) * 32 + rb]);
#pragma unroll
    for (int mt = 0; mt < MT; ++mt)
#pragma unroll
      for (int nt = 0; nt < 4; ++nt) acc[mt][nt] = MFMA16(af[mt], bfr[nt], acc[mt][nt]);
    __syncthreads();  // drains this step's prefetch + all ds reads
  }

#pragma unroll
  for (int mt = 0; mt < MT; ++mt) {
    const int gm = m0 + wm * (BM / 2) + mt * 16 + quad * 4;
#pragma unroll
    for (int nt = 0; nt < 4; ++nt) {
      const int gn = n0 + wn * 64 + nt * 16 + lrow;
#pragma unroll
      for (int r = 0; r < 4; ++r) C[(size_t)(gm + r) * N + gn] = (TC)(acc[mt][nt][r] * sc);
    }
  }
}

// ---------------- flash attention, transposed-S form (R8 + T5 setprio) -----
// BQ=128/block (4 waves x 32 q-rows), K-tiles of 64, max-free softmax.
// S^T = K·Q^T: per-lane P = 4 consecutive keys at one q-row -> b64 stores.
// Double-buffered K/V LDS (Qs reused as buffer 1), one barrier per tile.
__global__ __launch_bounds__(256, 2) void attn_kernel(const bf16* __restrict__ Qg,
                                                      const bf16* __restrict__ Kg,
                                                      const bf16* __restrict__ Vg,
                                                      const unsigned* __restrict__ bits,
                                                      bf16* __restrict__ Y) {
  constexpr int LQ = 72;
  __shared__ bf16 Qs[128 * LQ];  // after qf extraction: K/V buffer 1
  __shared__ bf16 Ks[64 * LQ];
  __shared__ bf16 Vts[64 * LQ];
  __shared__ bf16 Ps[4][32 * LQ];

  const int tid = threadIdx.x;
  const int lane = tid & 63;
  const int wv = tid >> 6;
  const int lrow = lane & 15, quad = lane >> 4;
  const int bh = blockIdx.y;
  const int b = bh >> 4, h = bh & 15;
  const int q0 = blockIdx.x * 128;

  const bf16* Qh = Qg + (size_t)bh * (SEQ * DK);
  const bf16* Kh = Kg + (size_t)bh * (SEQ * DK);
  const bf16* Vh = Vg + (size_t)bh * (SEQ * DK);

  // ---- stage Q tile (128x64, pre-scaled by QSCALE) ----
#pragma unroll
  for (int i = 0; i < 4; ++i) {
    int s = tid + i * 256;
    int row = s >> 3, c8 = (s & 7) * 8;
    *(uint4*)(&Qs[row * LQ + c8]) = *(const uint4*)(Qh + (size_t)(q0 + row) * DK + c8);
  }

  // ---- K/V prefetch-register plumbing ----
  const int krow = tid >> 3;  // 0..31 (second stripe: +32)
  const int kc8 = (tid & 7) * 8;
  const bf16* pk0 = Kh + (size_t)krow * DK + kc8;
  const bf16* pk1 = Kh + (size_t)(krow + 32) * DK + kc8;
  const int vn2 = tid & 31;   // dk-pair index
  const int vk2b = tid >> 5;  // key-pair base (k2 = vk2b + i*8)
  const bf16* pv0 = Vh + (size_t)(vk2b + 0) * 2 * DK + vn2 * 2;
  const bf16* pv1 = Vh + (size_t)(vk2b + 8) * 2 * DK + vn2 * 2;
  const bf16* pv2 = Vh + (size_t)(vk2b + 16) * 2 * DK + vn2 * 2;
  const bf16* pv3 = Vh + (size_t)(vk2b + 24) * 2 * DK + vn2 * 2;

  uint4 kr0, kr1;
  uint32_t va[4], vb[4];

  // tile 0 -> buffer 0 (Ks/Vts; independent of Qs)
  kr0 = *(const uint4*)(pk0);
  kr1 = *(const uint4*)(pk1);
  va[0] = *(const uint32_t*)(pv0);
  vb[0] = *(const uint32_t*)(pv0 + DK);
  va[1] = *(const uint32_t*)(pv1);
  vb[1] = *(const uint32_t*)(pv1 + DK);
  va[2] = *(const uint32_t*)(pv2);
  vb[2] = *(const uint32_t*)(pv2 + DK);
  va[3] = *(const uint32_t*)(pv3);
  vb[3] = *(const uint32_t*)(pv3 + DK);
  *(uint4*)(&Ks[krow * LQ + kc8]) = kr0;
  *(uint4*)(&Ks[(krow + 32) * LQ + kc8]) = kr1;
#pragma unroll
  for (int i = 0; i < 4; ++i) {
    uint32_t t0 = (va[i] & 0xffffu) | (vb[i] << 16);
    uint32_t t1 = (va[i] >> 16) | (vb[i] & 0xffff0000u);
    *(uint32_t*)(&Vts[(vn2 * 2) * LQ + (vk2b + i * 8) * 2]) = t0;
    *(uint32_t*)(&Vts[(vn2 * 2 + 1) * LQ + (vk2b + i * 8) * 2]) = t1;
  }
  __syncthreads();  // Q + tile0 staged

  bf16x8 qf[2][2];  // B-frag for S^T: [q-row tile][ks]
#pragma unroll
  for (int nt = 0; nt < 2; ++nt)
#pragma unroll
    for (int ks = 0; ks < 2; ++ks)
      qf[nt][ks] = *(const bf16x8*)(&Qs[(wv * 32 + nt * 16 + lrow) * LQ + ks * 32 + quad * 8]);
  __syncthreads();  // all qf reads done -> Qs reusable as buffer 1

  const f32x4 fz = {0.f, 0.f, 0.f, 0.f};
  f32x4 of_t[4][2];  // O^T: [dk-tile][q-row-tile]
#pragma unroll
  for (int i = 0; i < 4; ++i)
#pragma unroll
    for (int j = 0; j < 2; ++j) of_t[i][j] = fz;
  float lsum[2] = {0.f, 0.f};  // per-lane partial row sums (q-row nt*16+lrow)

  const unsigned* bitrow = bits + (size_t)b * SEQ * (SEQ / 32);

  for (int kt = 0; kt < 32; ++kt) {
    const int cur = kt & 1;
    bf16* kb = cur ? Qs : Ks;
    bf16* vbuf = cur ? (Qs + 64 * LQ) : Vts;
    // prefetch next tile (global; overlaps the whole compute body)
    if (kt + 1 < 32) {
      const size_t adv = (size_t)(kt + 1) * 64 * DK;
      kr0 = *(const uint4*)(pk0 + adv);
      kr1 = *(const uint4*)(pk1 + adv);
      va[0] = *(const uint32_t*)(pv0 + adv);
      vb[0] = *(const uint32_t*)(pv0 + adv + DK);
      va[1] = *(const uint32_t*)(pv1 + adv);
      vb[1] = *(const uint32_t*)(pv1 + adv + DK);
      va[2] = *(const uint32_t*)(pv2 + adv);
      vb[2] = *(const uint32_t*)(pv2 + adv + DK);
      va[3] = *(const uint32_t*)(pv3 + adv);
      vb[3] = *(const uint32_t*)(pv3 + adv + DK);
    }
    // mask: one 64-bit word per q-row covers this tile's 64 keys
    uint2 mwn[2];
#pragma unroll
    for (int nt = 0; nt < 2; ++nt) {
      int row = q0 + wv * 32 + nt * 16 + lrow;
      mwn[nt] = *(const uint2*)(bitrow + (size_t)row * (SEQ / 32) + kt * 2);
    }

    // ---- S^T = K @ Q^T (A = K-frag, B = Q-frag) ----
    f32x4 st[4][2];
#pragma unroll
    for (int mt = 0; mt < 4; ++mt)
#pragma unroll
      for (int nt = 0; nt < 2; ++nt) st[mt][nt] = fz;
    __builtin_amdgcn_s_setprio(1);
#pragma unroll
    for (int ks = 0; ks < 2; ++ks) {
#pragma unroll
      for (int mt = 0; mt < 4; ++mt) {
        bf16x8 kfv = *(const bf16x8*)(kb + (mt * 16 + lrow) * LQ + ks * 32 + quad * 8);
#pragma unroll
        for (int nt = 0; nt < 2; ++nt) st[mt][nt] = MFMA16(kfv, qf[nt][ks], st[mt][nt]);
      }
    }
    __builtin_amdgcn_s_setprio(0);

    // ---- max-free softmax; packed b64 P stores ----
    // lane's values: q-row = nt*16+lrow, keys = mt*16+quad*4+{0..3}
#pragma unroll
    for (int nt = 0; nt < 2; ++nt) {
      uint32_t ux = mwn[nt].x >> (quad * 4);
      uint32_t uy = mwn[nt].y >> (quad * 4);
      float psum = 0.f;
#pragma unroll
      for (int mt = 0; mt < 4; ++mt) {
        uint32_t u = (mt & 2) ? uy : ux;
        int sh = (mt & 1) << 4;
        bf16x4 pk;
#pragma unroll
        for (int r = 0; r < 4; ++r) {
          float p = EXP2(st[mt][nt][r]);
          p = ((u >> (sh + r)) & 1u) ? p : 0.f;
          psum += p;
          pk[r] = (bf16)p;
        }
        *(bf16x4*)(&Ps[wv][(nt * 16 + lrow) * LQ + mt * 16 + quad * 4]) = pk;
      }
      lsum[nt] += psum;
    }

    // ---- O^T += V^T @ P^T : A = Vt-frag, B = P-frag (both b128) ----
    __builtin_amdgcn_s_setprio(1);
#pragma unroll
    for (int ks = 0; ks < 2; ++ks) {
      bf16x8 avf[4], bpf[2];
#pragma unroll
      for (int dkt = 0; dkt < 4; ++dkt)
        avf[dkt] = *(const bf16x8*)(vbuf + (dkt * 16 + lrow) * LQ + ks * 32 + quad * 8);
#pragma unroll
      for (int rt = 0; rt < 2; ++rt)
        bpf[rt] = *(const bf16x8*)(&Ps[wv][(rt * 16 + lrow) * LQ + ks * 32 + quad * 8]);
#pragma unroll
      for (int dkt = 0; dkt < 4; ++dkt)
#pragma unroll
        for (int rt = 0; rt < 2; ++rt) of_t[dkt][rt] = MFMA16(avf[dkt], bpf[rt], of_t[dkt][rt]);
    }
    __builtin_amdgcn_s_setprio(0);

    // stage next tile into the other buffer
    if (kt + 1 < 32) {
      bf16* kbn = cur ? Ks : Qs;
      bf16* vbn = cur ? Vts : (Qs + 64 * LQ);
      *(uint4*)(kbn + krow * LQ + kc8) = kr0;
      *(uint4*)(kbn + (krow + 32) * LQ + kc8) = kr1;
#pragma unroll
      for (int i = 0; i < 4; ++i) {
        uint32_t t0 = (va[i] & 0xffffu) | (vb[i] << 16);
        uint32_t t1 = (va[i] >> 16) | (vb[i] & 0xffff0000u);
        *(uint32_t*)(vbn + (vn2 * 2) * LQ + (vk2b + i * 8) * 2) = t0;
        *(uint32_t*)(vbn + (vn2 * 2 + 1) * LQ + (vk2b + i * 8) * 2) = t1;
      }
    }
    __syncthreads();  // single barrier per tile
  }

  // ---- row-sum: reduce per-lane partials across quads (2 shuffles) ----
  float linv[2];
#pragma unroll
  for (int nt = 0; nt < 2; ++nt) {
    float v = lsum[nt];
    v += __shfl_xor(v, 16);
    v += __shfl_xor(v, 32);
    linv[nt] = 1.0f / fmaxf(v, 1e-20f);
  }

  // ---- epilogue: O^T C-layout col = q-row (lrow), row = dk (quad*4+j) ----
#pragma unroll
  for (int dkt = 0; dkt < 4; ++dkt)
#pragma unroll
    for (int rt = 0; rt < 2; ++rt) {
      bf16x4 o;
#pragma unroll
      for (int j = 0; j < 4; ++j) o[j] = (bf16)(of_t[dkt][rt][j] * linv[rt]);
      const int row = q0 + wv * 32 + rt * 16 + lrow;
      *(bf16x4*)(&Y[((size_t)b * SEQ + row) * DIM + h * 64 + dkt * 16 + quad * 4]) = o;
    }
}

// ---------------------------------------------------------------------------
extern "C" void kernel_launch(void* const* d_in, const int* in_sizes, int n_in,
                              void* d_out, int out_size, void* d_ws, size_t ws_size,
                              hipStream_t stream) {
  const float* query = (const float*)d_in[0];
  const float* key = (const float*)d_in[1];
  const float* value = (const float*)d_in[2];
  const float* Wqkv = (const float*)d_in[3];
  const float* Wout = (const float*)d_in[4];
  const int* mask = (const int*)d_in[5];
  float* out = (float*)d_out;

  // workspace map (53 MB total; y aliases dead qin region)
  char* ws = (char*)d_ws;
  bf16* qin = (bf16*)(ws);             //  8 MB  bf16 query (dead after QKV GEMM)
  bf16* kin = (bf16*)(ws + 8388608);   //  8 MB  bf16 key
  bf16* vin = (bf16*)(ws + 16777216);  //  8 MB  bf16 value
  bf16* Wq = (bf16*)(ws + 25165824);   //  2 MB  bf16 Wqkv
  bf16* Wo = (bf16*)(ws + 27262976);   //  2 MB  bf16 Wout
  bf16* q = (bf16*)(ws + 29360128);    //  8 MB  projected q (pre-scaled)
  bf16* k = (bf16*)(ws + 37748736);    //  8 MB
  bf16* v = (bf16*)(ws + 46137344);    //  8 MB
  bf16* y = (bf16*)(ws);               //  8 MB  attn out (aliases qin)
  unsigned long long* bits64 = (unsigned long long*)(ws + 54525952);  // 1 MB

  // 1) mask -> bits
  mask_bits_kernel<<<(BATCH * SEQ * SEQ) / 256, 256, 0, stream>>>(mask, bits64);

  // 2) fp32 -> bf16 one-shot convert (q/k/v activations + both weights)
  cvt_bf16_kernel<<<dim3(2048, 5), 256, 0, stream>>>(query, key, value, Wqkv, Wout,
                                                     qin, kin, vin, Wq, Wo);

  // 3) fused QKV projection (q scaled by QSCALE in epilogue, z==0 only)
  gemm_bt_lds<128, 32, 3, bf16>
      <<<dim3(8, 32, 3), 256, 0, stream>>>(qin, kin, vin, Wq, q, k, v, QSCALE);

  // 4) flash attention (16 q-tiles x 32 heads)
  attn_kernel<<<dim3(16, 32), 256, 0, stream>>>(q, k, v, (const unsigned*)bits64, y);

  // 5) output projection -> fp32 out; BM=64 -> 512 blocks (2 blocks/CU)
  gemm_bt_lds<64, 64, 1, float>
      <<<dim3(8, 64, 1), 256, 0, stream>>>(y, y, y, Wo, out, out, out, 1.0f);
}